// Round 4
// baseline (560.541 us; speedup 1.0000x reference)
//
#include <hip/hip_runtime.h>

typedef unsigned short u16;
typedef unsigned int   u32;
typedef short bf16x8 __attribute__((ext_vector_type(8)));
typedef float f32x4  __attribute__((ext_vector_type(4)));

#define SQ 2048            // sequence length
#define DMODEL 2048        // embed dim
#define NROWS 4096         // b*s
#define LAMBDA_INIT 0.7836057665316245f
#define OUT_SCALE   0.21639423346837552f   // 1 - LAMBDA_INIT
#define CSC 0.18033688011112042f           // 0.125 * log2(e): softmax in log2 domain

// ---------- helpers ----------
__device__ __forceinline__ float bf2f(u16 u) {
    union { u32 u; float f; } x; x.u = ((u32)u) << 16; return x.f;
}
__device__ __forceinline__ u16 f2bf(float f) {
    union { float f; u32 u; } x; x.f = f;
    u32 r = x.u + 0x7fffu + ((x.u >> 16) & 1u);   // RNE
    return (u16)(r >> 16);
}

// async global->LDS, 16B per lane. lds base must be wave-uniform; HW scatters
// lane i -> base + 16*i.  [m03/m97-verified path]
__device__ __forceinline__ void gload_lds16(const void* g, void* l) {
    __builtin_amdgcn_global_load_lds((const __attribute__((address_space(1))) void*)g,
                                     (__attribute__((address_space(3))) void*)l,
                                     16, 0, 0);
}

// ---------- W transpose + bf16 convert: Wt[n][k] = bf16(W[k][n]) ----------
__global__ __launch_bounds__(256) void transpose_w(const float* __restrict__ W0,
                                                   const float* __restrict__ W1,
                                                   const float* __restrict__ W2,
                                                   const float* __restrict__ W3,
                                                   u16* __restrict__ out) {
    __shared__ float tile[32][33];
    const int z = blockIdx.z;
    const float* W = (z == 0) ? W0 : (z == 1) ? W1 : (z == 2) ? W2 : W3;
    u16* O = out + (size_t)z * DMODEL * DMODEL;
    const int tx = threadIdx.x, ty = threadIdx.y;
    const int bx = blockIdx.x, by = blockIdx.y;
#pragma unroll
    for (int j = 0; j < 4; ++j)
        tile[ty + j * 8][tx] = W[(size_t)(by * 32 + ty + j * 8) * DMODEL + bx * 32 + tx];
    __syncthreads();
#pragma unroll
    for (int j = 0; j < 4; ++j)
        O[(size_t)(bx * 32 + ty + j * 8) * DMODEL + by * 32 + tx] = f2bf(tile[tx][ty + j * 8]);
}

// ---------- x -> bf16 ----------
__global__ __launch_bounds__(256) void cvt_x(const float* __restrict__ x, u16* __restrict__ xb) {
    const size_t i = ((size_t)blockIdx.x * 256 + threadIdx.x) * 8;
    float4 a = *(const float4*)(x + i);
    float4 b = *(const float4*)(x + i + 4);
    uint4 o;
    o.x = (u32)f2bf(a.x) | ((u32)f2bf(a.y) << 16);
    o.y = (u32)f2bf(a.z) | ((u32)f2bf(a.w) << 16);
    o.z = (u32)f2bf(b.x) | ((u32)f2bf(b.y) << 16);
    o.w = (u32)f2bf(b.z) | ((u32)f2bf(b.w) << 16);
    *(uint4*)(xb + i) = o;
}

// ---------- MFMA GEMM (m97 pattern): C = A(MxK) x Bt(NxK)^T ----------
template <bool OUT_BF16>
__global__ __launch_bounds__(256) void gemm_bt(const u16* __restrict__ A,
                                               const u16* __restrict__ Bt0,
                                               void* __restrict__ C0) {
    __shared__ u16 As[128 * 32];   // 8 KB, NO padding (lds-scatter is lane-contiguous)
    __shared__ u16 Bs[128 * 32];
    const int tid  = threadIdx.x;
    const int lane = tid & 63, wave = tid >> 6;
    const int wm = wave & 1, wn = wave >> 1;
    const int l15 = lane & 15, quad = lane >> 4;
    const int tm = blockIdx.y * 128, tn = blockIdx.x * 128;
    const u16* Bt = Bt0 + (size_t)blockIdx.z * DMODEL * DMODEL;

    const int r_l = lane >> 2, c_l = lane & 3;   // row-in-chunk, col-group

    f32x4 acc[4][4] = {};

    for (int k0 = 0; k0 < DMODEL; k0 += 32) {
#pragma unroll
        for (int c = 0; c < 2; ++c) {
            const int chunk = wave * 2 + c;
            const int row = chunk * 16 + r_l;
            gload_lds16(A  + (size_t)(tm + row) * DMODEL + k0 + c_l * 8, &As[chunk * 512]);
            gload_lds16(Bt + (size_t)(tn + row) * DMODEL + k0 + c_l * 8, &Bs[chunk * 512]);
        }
        __syncthreads();
        bf16x8 af[4], bfr[4];
#pragma unroll
        for (int mb = 0; mb < 4; ++mb)
            af[mb] = *(const bf16x8*)(As + (wm * 64 + mb * 16 + l15) * 32 + quad * 8);
#pragma unroll
        for (int nb = 0; nb < 4; ++nb)
            bfr[nb] = *(const bf16x8*)(Bs + (wn * 64 + nb * 16 + l15) * 32 + quad * 8);
#pragma unroll
        for (int mb = 0; mb < 4; ++mb)
#pragma unroll
            for (int nb = 0; nb < 4; ++nb)
                acc[mb][nb] = __builtin_amdgcn_mfma_f32_16x16x32_bf16(af[mb], bfr[nb], acc[mb][nb], 0, 0, 0);
        __syncthreads();
    }
#pragma unroll
    for (int mb = 0; mb < 4; ++mb)
#pragma unroll
        for (int nb = 0; nb < 4; ++nb)
#pragma unroll
            for (int r = 0; r < 4; ++r) {
                const int row = tm + wm * 64 + mb * 16 + quad * 4 + r;
                const int col = tn + wn * 64 + nb * 16 + l15;
                const float v = acc[mb][nb][r];
                if (OUT_BF16) {
                    u16* C = (u16*)C0 + (size_t)blockIdx.z * NROWS * DMODEL;
                    C[(size_t)row * DMODEL + col] = f2bf(v);
                } else {
                    float* C = (float*)C0;
                    C[(size_t)row * DMODEL + col] = v;
                }
            }
}

// ---------- RoPE in place on bf16 q or k ----------
__global__ __launch_bounds__(256) void rope_kernel(u16* __restrict__ qw, u16* __restrict__ kw) {
    const int row = blockIdx.x;
    const int spos = row & (SQ - 1);
    u16* buf = blockIdx.y ? kw : qw;
    for (int idx = threadIdx.x; idx < 1024; idx += 256) {
        const int h2 = idx >> 5, i = idx & 31;
        const size_t base = (size_t)row * DMODEL + h2 * 64 + 2 * i;
        const float x1 = bf2f(buf[base]), x2 = bf2f(buf[base + 1]);
        const float f = (float)spos * exp2f(-0.41524101186092034f * (float)i);
        const float c = cosf(f), sn = sinf(f);
        buf[base]     = f2bf(x1 * c - x2 * sn);
        buf[base + 1] = f2bf(x2 * c + x1 * sn);
    }
}

// ---------- lambda scalar ----------
__global__ void lam_kernel(const float* __restrict__ lq1, const float* __restrict__ lk1,
                           const float* __restrict__ lq2, const float* __restrict__ lk2,
                           float* __restrict__ out) {
    const int l = threadIdx.x;  // 64
    float v1 = lq1[l] * lk1[l];
    float v2 = lq2[l] * lk2[l];
#pragma unroll
    for (int off = 32; off; off >>= 1) {
        v1 += __shfl_xor(v1, off);
        v2 += __shfl_xor(v2, off);
    }
    if (l == 0) out[0] = __expf(v1) - __expf(v2) + LAMBDA_INIT;
}

// ---------- V transpose: vtg[bh][128 dims][2048 keys] ----------
__global__ __launch_bounds__(256) void vtrans(const u16* __restrict__ vb, u16* __restrict__ vtg) {
    __shared__ u16 tile[64][72];
    const int bh = blockIdx.z;
    const int b = bh >> 4, h = bh & 15;
    const int s0 = blockIdx.x * 64, d0 = blockIdx.y * 64;
    const size_t rowbase = (size_t)b * SQ;
    const int tid = threadIdx.x;
#pragma unroll
    for (int it = 0; it < 2; ++it) {
        const int slot = it * 256 + tid;
        const int key = slot >> 3, dg = slot & 7;
        *(uint4*)&tile[key][dg * 8] =
            *(const uint4*)(vb + (rowbase + s0 + key) * DMODEL + h * 128 + d0 + dg * 8);
    }
    __syncthreads();
#pragma unroll
    for (int it = 0; it < 2; ++it) {
        const int slot = it * 256 + tid;
        const int d = slot >> 3, kg = slot & 7;
        u16 e[8];
#pragma unroll
        for (int j = 0; j < 8; ++j) e[j] = tile[kg * 8 + j][d];
        uint4 o;
        o.x = (u32)e[0] | ((u32)e[1] << 16);
        o.y = (u32)e[2] | ((u32)e[3] << 16);
        o.z = (u32)e[4] | ((u32)e[5] << 16);
        o.w = (u32)e[6] | ((u32)e[7] << 16);
        *(uint4*)(vtg + ((size_t)bh * 128 + d0 + d) * SQ + s0 + kg * 8) = o;
    }
}

// ---------- MFMA flash attention (dual softmax) + fused combine/RMSNorm ----------
// grid (32 bh, 16 pairs): bh fastest -> XCD r sees only bh%8==r (4 bh, 4 MB K+V = L2).
// Balanced pairing: block does strips {pair, 31-pair} = 33 tiles total.
// K/V staged async via global_load_lds (source-side xor swizzle), double-buffered:
// prefetch g+1 right after the barrier; barrier at g+2 drains it (full-tile hiding).
__global__ __launch_bounds__(256) void attn_kernel(const u16* __restrict__ qw,
                                                   const u16* __restrict__ kw,
                                                   const u16* __restrict__ vtg,
                                                   const float* __restrict__ lamp,
                                                   const float* __restrict__ lnw,
                                                   const float* __restrict__ lnb,
                                                   u16* __restrict__ yb) {
    __shared__ u16 Ks[2][64 * 128];   // [buf][key][16 swizzled col-groups of 8]
    __shared__ u16 Vts[2][128 * 64];  // [buf][dim][8 swizzled key-groups of 8]
    __shared__ u16 Pls[4][16 * 72];   // per-wave [q16][64 keys + 8 pad]

    const int tid = threadIdx.x, lane = tid & 63, wave = tid >> 6;
    const int l15 = lane & 15, quad = lane >> 4;
    const int bh = blockIdx.x, b = bh >> 4, h = bh & 15;
    const int pair = blockIdx.y;
    const size_t rowbase = (size_t)b * SQ;
    const int coff = h * 128;
    const float lam = lamp[0];
    const int nt0 = pair + 1;

    // per-lane staging source offsets (swizzle applied on the SOURCE side so the
    // lane-contiguous LDS scatter lands data at the swizzled slot)
    int kOff[4], vOff[4];
#pragma unroll
    for (int i = 0; i < 4; ++i) {
        const int cK  = wave * 4 + i;
        const int key = cK * 4 + (lane >> 4);          // 4 key-rows per chunk
        const int cg  = (lane & 15) ^ (key & 7);       // logical col-group for phys slot lane&15
        kOff[i] = key * DMODEL + coff + cg * 8;
        const int dd  = cK * 8 + (lane >> 3);          // 8 dim-rows per chunk
        const int kg  = (lane & 7) ^ (lane >> 3);      // dd&7 == lane>>3
        vOff[i] = dd * SQ + kg * 8;
    }
    const size_t kBase = rowbase * DMODEL;
    const size_t vBase = (size_t)bh * 128 * SQ;

    auto stageKV = [&](int t0, int d) {
#pragma unroll
        for (int i = 0; i < 4; ++i) {
            gload_lds16(kw + kBase + (size_t)t0 * DMODEL + kOff[i], &Ks[d][(wave * 4 + i) * 512]);
            gload_lds16(vtg + vBase + t0 + vOff[i], &Vts[d][(wave * 4 + i) * 512]);
        }
    };

    int g = 0;
    stageKV(0, 0);   // prefetch first tile

#pragma unroll 1
    for (int s = 0; s < 2; ++s) {
        const int strip = s ? (31 - pair) : pair;
        const int q0 = strip * 64;
        const int nt = strip + 1;

        // Q fragments (A layout: m=lane&15, k=quad*8+j), persistent per strip
        bf16x8 qf[2][2];
        {
            const size_t qbase = (rowbase + q0 + wave * 16 + l15) * DMODEL + coff + quad * 8;
#pragma unroll
            for (int hf = 0; hf < 2; ++hf)
#pragma unroll
                for (int ks = 0; ks < 2; ++ks)
                    qf[hf][ks] = *(const bf16x8*)(qw + qbase + hf * 64 + ks * 32);
        }

        f32x4 O[2][8] = {};
        float mm[2][4], ll[2][4];
#pragma unroll
        for (int hf = 0; hf < 2; ++hf)
#pragma unroll
            for (int r = 0; r < 4; ++r) { mm[hf][r] = -1e30f; ll[hf][r] = 0.f; }

        for (int t = 0; t < nt; ++t, ++g) {
            const int t0 = t * 64;
            __syncthreads();            // drains prefetch of tile g; fences Pls/K/V reuse
            // prefetch next global tile into the other buffer
            {
                const int gn = g + 1;
                if (gn < 33) {
                    const int tn = (gn < nt0) ? gn : gn - nt0;
                    stageKV(tn * 64, gn & 1);
                }
            }
            const u16* __restrict__ KsB = Ks[g & 1];
            const u16* __restrict__ VtB = Vts[g & 1];
            const bool maskt = (t == nt - 1);   // only diagonal tile needs masking

#pragma unroll
            for (int hf = 0; hf < 2; ++hf) {
                // ---- S = Q_hf K_hf^T (16 q x 64 keys per wave), log2-domain scale ----
                f32x4 S[4] = {};
#pragma unroll
                for (int nb = 0; nb < 4; ++nb)
#pragma unroll
                    for (int ks = 0; ks < 2; ++ks) {
                        const int cgp = (hf * 8 + ks * 4 + quad) ^ (l15 & 7);
                        bf16x8 kf = *(const bf16x8*)&KsB[(nb * 16 + l15) * 128 + cgp * 8];
                        S[nb] = __builtin_amdgcn_mfma_f32_16x16x32_bf16(qf[hf][ks], kf, S[nb], 0, 0, 0);
                    }
                // ---- scale (log2 domain) + causal mask + row max ----
                float mt[4];
#pragma unroll
                for (int r = 0; r < 4; ++r) mt[r] = -1e30f;
#pragma unroll
                for (int nb = 0; nb < 4; ++nb)
#pragma unroll
                    for (int r = 0; r < 4; ++r) {
                        float sv = S[nb][r] * CSC;
                        if (maskt && (nb * 16 + l15 > wave * 16 + quad * 4 + r)) sv = -1e30f;
                        S[nb][r] = sv;
                        mt[r] = fmaxf(mt[r], sv);
                    }
#pragma unroll
                for (int r = 0; r < 4; ++r)
#pragma unroll
                    for (int off = 1; off < 16; off <<= 1)
                        mt[r] = fmaxf(mt[r], __shfl_xor(mt[r], off));
                // ---- online softmax update (exp2; truncation-quantized bf16 P) ----
                float alpha[4], ps[4];
#pragma unroll
                for (int r = 0; r < 4; ++r) {
                    const float mn = fmaxf(mm[hf][r], mt[r]);
                    alpha[r] = exp2f(mm[hf][r] - mn);
                    mm[hf][r] = mn;
                    ps[r] = 0.f;
                }
#pragma unroll
                for (int nb = 0; nb < 4; ++nb)
#pragma unroll
                    for (int r = 0; r < 4; ++r) {
                        const float p = exp2f(S[nb][r] - mm[hf][r]);
                        const u32 pu = __builtin_bit_cast(u32, p);
                        ps[r] += __builtin_bit_cast(float, pu & 0xffff0000u); // quantized sum
                        Pls[wave][(quad * 4 + r) * 72 + nb * 16 + l15] = (u16)(pu >> 16);
                    }
#pragma unroll
                for (int r = 0; r < 4; ++r) {
#pragma unroll
                    for (int off = 1; off < 16; off <<= 1) ps[r] += __shfl_xor(ps[r], off);
                    ll[hf][r] = ll[hf][r] * alpha[r] + ps[r];
                }
                // ---- rescale O, then O += P V ----
#pragma unroll
                for (int nb = 0; nb < 8; ++nb)
#pragma unroll
                    for (int r = 0; r < 4; ++r) O[hf][nb][r] *= alpha[r];
                bf16x8 pf[2];
#pragma unroll
                for (int ks = 0; ks < 2; ++ks)
                    pf[ks] = *(const bf16x8*)&Pls[wave][l15 * 72 + ks * 32 + quad * 8];
#pragma unroll
                for (int nb = 0; nb < 8; ++nb)
#pragma unroll
                    for (int ks = 0; ks < 2; ++ks) {
                        const int kgp = (ks * 4 + quad) ^ (l15 & 7);
                        bf16x8 vf = *(const bf16x8*)&VtB[(nb * 16 + l15) * 64 + kgp * 8];
                        O[hf][nb] = __builtin_amdgcn_mfma_f32_16x16x32_bf16(pf[ks], vf, O[hf][nb], 0, 0, 0);
                    }
            }
        }

        // ---- epilogue: y = rmsnorm(O1/l1 - lam*O2/l2) * w + b, * OUT_SCALE ----
        float inl1[4], inl2[4];
#pragma unroll
        for (int r = 0; r < 4; ++r) { inl1[r] = 1.f / ll[0][r]; inl2[r] = 1.f / ll[1][r]; }
        float vv[8][4], ss[4] = {0.f, 0.f, 0.f, 0.f};
#pragma unroll
        for (int nb = 0; nb < 8; ++nb)
#pragma unroll
            for (int r = 0; r < 4; ++r) {
                const float v = O[0][nb][r] * inl1[r] - lam * O[1][nb][r] * inl2[r];
                vv[nb][r] = v;
                ss[r] += v * v;
            }
#pragma unroll
        for (int r = 0; r < 4; ++r) {
#pragma unroll
            for (int off = 1; off < 16; off <<= 1) ss[r] += __shfl_xor(ss[r], off);
            ss[r] = rsqrtf(ss[r] * (1.f / 128.f) + 1e-8f) * OUT_SCALE;
        }
#pragma unroll
        for (int nb = 0; nb < 8; ++nb) {
            const int d = nb * 16 + l15;
            const float w = lnw[d], bb = lnb[d] * OUT_SCALE;
#pragma unroll
            for (int r = 0; r < 4; ++r) {
                const size_t row = rowbase + q0 + wave * 16 + quad * 4 + r;
                yb[row * DMODEL + coff + d] = f2bf(vv[nb][r] * ss[r] * w + bb);
            }
        }
    }
}

// ---------- workspace layout (bytes) ----------
#define WT_OFF   0ull                 // 4 x 2048x2048 bf16 = 32 MB
#define XB_OFF   33554432ull          // 4096x2048 bf16 (xb, reused as yb)
#define Q_OFF    50331648ull          // 4096x2048 bf16
#define K_OFF    67108864ull
#define V_OFF    83886080ull
#define VT_OFF   100663296ull         // 32 bh x 128 x 2048 bf16 = 16 MB
#define LAM_OFF  117440512ull
#define WS_NEED  117440768ull

extern "C" void kernel_launch(void* const* d_in, const int* in_sizes, int n_in,
                              void* d_out, int out_size, void* d_ws, size_t ws_size,
                              hipStream_t stream) {
    if (ws_size < WS_NEED) return;
    const float* x   = (const float*)d_in[0];
    const float* Wq  = (const float*)d_in[1];
    const float* Wk  = (const float*)d_in[2];
    const float* Wv  = (const float*)d_in[3];
    const float* Wo  = (const float*)d_in[4];
    const float* lq1 = (const float*)d_in[5];
    const float* lk1 = (const float*)d_in[6];
    const float* lq2 = (const float*)d_in[7];
    const float* lk2 = (const float*)d_in[8];
    const float* lnw = (const float*)d_in[9];
    const float* lnb = (const float*)d_in[10];

    char* ws = (char*)d_ws;
    u16* wt  = (u16*)(ws + WT_OFF);
    u16* xb  = (u16*)(ws + XB_OFF);   // also yb after attention
    u16* qb  = (u16*)(ws + Q_OFF);
    u16* kb  = (u16*)(ws + K_OFF);
    u16* vb  = (u16*)(ws + V_OFF);
    u16* vtg = (u16*)(ws + VT_OFF);
    float* lam = (float*)(ws + LAM_OFF);
    float* out = (float*)d_out;

    // 1. transpose + convert weights
    transpose_w<<<dim3(64, 64, 4), dim3(32, 8, 1), 0, stream>>>(Wq, Wk, Wv, Wo, wt);
    // 2. x -> bf16
    cvt_x<<<dim3(4096), dim3(256), 0, stream>>>(x, xb);
    // 3. q,k,v GEMMs (bf16 out)
    gemm_bt<true><<<dim3(16, 32, 3), dim3(256), 0, stream>>>(xb, wt, qb);
    // 4. RoPE in place on q and k
    rope_kernel<<<dim3(4096, 2), dim3(256), 0, stream>>>(qb, kb);
    // 5. lambda
    lam_kernel<<<dim3(1), dim3(64), 0, stream>>>(lq1, lk1, lq2, lk2, lam);
    // 6. V transpose for PV MFMA B-operand
    vtrans<<<dim3(32, 2, 32), dim3(256), 0, stream>>>(vb, vtg);
    // 7. MFMA flash attention (dbuf async staging, XCD-local grid) -> yb
    attn_kernel<<<dim3(32, 16), dim3(256), 0, stream>>>(qb, kb, vtg, lam, lnw, lnb, xb);
    // 8. out = y @ Wo  (f32 out)
    gemm_bt<false><<<dim3(16, 32, 1), dim3(256), 0, stream>>>(xb, wt + 3ull * DMODEL * DMODEL, out);
}

// Round 5
// 498.595 us; speedup vs baseline: 1.1242x; 1.1242x over previous
//
#include <hip/hip_runtime.h>

typedef unsigned short u16;
typedef unsigned int   u32;
typedef short bf16x8 __attribute__((ext_vector_type(8)));
typedef float f32x4  __attribute__((ext_vector_type(4)));

#define SQ 2048            // sequence length
#define DMODEL 2048        // embed dim
#define NROWS 4096         // b*s
#define LAMBDA_INIT 0.7836057665316245f
#define OUT_SCALE   0.21639423346837552f   // 1 - LAMBDA_INIT
#define CSC 0.18033688011112042f           // 0.125 * log2(e): softmax in log2 domain

// ---------- helpers ----------
__device__ __forceinline__ float bf2f(u16 u) {
    union { u32 u; float f; } x; x.u = ((u32)u) << 16; return x.f;
}
__device__ __forceinline__ u16 f2bf(float f) {
    union { float f; u32 u; } x; x.f = f;
    u32 r = x.u + 0x7fffu + ((x.u >> 16) & 1u);   // RNE
    return (u16)(r >> 16);
}

// async global->LDS, 16B per lane. lds base must be wave-uniform; HW scatters
// lane i -> base + 16*i.  [m03/m97-verified path]
__device__ __forceinline__ void gload_lds16(const void* g, void* l) {
    __builtin_amdgcn_global_load_lds((const __attribute__((address_space(1))) void*)g,
                                     (__attribute__((address_space(3))) void*)l,
                                     16, 0, 0);
}

// ---------- W transpose + bf16 convert: Wt[n][k] = bf16(W[k][n]) ----------
__global__ __launch_bounds__(256) void transpose_w(const float* __restrict__ W0,
                                                   const float* __restrict__ W1,
                                                   const float* __restrict__ W2,
                                                   const float* __restrict__ W3,
                                                   u16* __restrict__ out) {
    __shared__ float tile[32][33];
    const int z = blockIdx.z;
    const float* W = (z == 0) ? W0 : (z == 1) ? W1 : (z == 2) ? W2 : W3;
    u16* O = out + (size_t)z * DMODEL * DMODEL;
    const int tx = threadIdx.x, ty = threadIdx.y;
    const int bx = blockIdx.x, by = blockIdx.y;
#pragma unroll
    for (int j = 0; j < 4; ++j)
        tile[ty + j * 8][tx] = W[(size_t)(by * 32 + ty + j * 8) * DMODEL + bx * 32 + tx];
    __syncthreads();
#pragma unroll
    for (int j = 0; j < 4; ++j)
        O[(size_t)(bx * 32 + ty + j * 8) * DMODEL + by * 32 + tx] = f2bf(tile[tx][ty + j * 8]);
}

// ---------- x -> bf16 ----------
__global__ __launch_bounds__(256) void cvt_x(const float* __restrict__ x, u16* __restrict__ xb) {
    const size_t i = ((size_t)blockIdx.x * 256 + threadIdx.x) * 8;
    float4 a = *(const float4*)(x + i);
    float4 b = *(const float4*)(x + i + 4);
    uint4 o;
    o.x = (u32)f2bf(a.x) | ((u32)f2bf(a.y) << 16);
    o.y = (u32)f2bf(a.z) | ((u32)f2bf(a.w) << 16);
    o.z = (u32)f2bf(b.x) | ((u32)f2bf(b.y) << 16);
    o.w = (u32)f2bf(b.z) | ((u32)f2bf(b.w) << 16);
    *(uint4*)(xb + i) = o;
}

// ---------- MFMA GEMM (m97 pattern): C = A(MxK) x Bt(NxK)^T ----------
template <bool OUT_BF16>
__global__ __launch_bounds__(256) void gemm_bt(const u16* __restrict__ A,
                                               const u16* __restrict__ Bt0,
                                               void* __restrict__ C0) {
    __shared__ u16 As[128 * 32];   // 8 KB, NO padding (lds-scatter is lane-contiguous)
    __shared__ u16 Bs[128 * 32];
    const int tid  = threadIdx.x;
    const int lane = tid & 63, wave = tid >> 6;
    const int wm = wave & 1, wn = wave >> 1;
    const int l15 = lane & 15, quad = lane >> 4;
    const int tm = blockIdx.y * 128, tn = blockIdx.x * 128;
    const u16* Bt = Bt0 + (size_t)blockIdx.z * DMODEL * DMODEL;

    const int r_l = lane >> 2, c_l = lane & 3;   // row-in-chunk, col-group

    f32x4 acc[4][4] = {};

    for (int k0 = 0; k0 < DMODEL; k0 += 32) {
#pragma unroll
        for (int c = 0; c < 2; ++c) {
            const int chunk = wave * 2 + c;
            const int row = chunk * 16 + r_l;
            gload_lds16(A  + (size_t)(tm + row) * DMODEL + k0 + c_l * 8, &As[chunk * 512]);
            gload_lds16(Bt + (size_t)(tn + row) * DMODEL + k0 + c_l * 8, &Bs[chunk * 512]);
        }
        __syncthreads();
        bf16x8 af[4], bfr[4];
#pragma unroll
        for (int mb = 0; mb < 4; ++mb)
            af[mb] = *(const bf16x8*)(As + (wm * 64 + mb * 16 + l15) * 32 + quad * 8);
#pragma unroll
        for (int nb = 0; nb < 4; ++nb)
            bfr[nb] = *(const bf16x8*)(Bs + (wn * 64 + nb * 16 + l15) * 32 + quad * 8);
#pragma unroll
        for (int mb = 0; mb < 4; ++mb)
#pragma unroll
            for (int nb = 0; nb < 4; ++nb)
                acc[mb][nb] = __builtin_amdgcn_mfma_f32_16x16x32_bf16(af[mb], bfr[nb], acc[mb][nb], 0, 0, 0);
        __syncthreads();
    }
#pragma unroll
    for (int mb = 0; mb < 4; ++mb)
#pragma unroll
        for (int nb = 0; nb < 4; ++nb)
#pragma unroll
            for (int r = 0; r < 4; ++r) {
                const int row = tm + wm * 64 + mb * 16 + quad * 4 + r;
                const int col = tn + wn * 64 + nb * 16 + l15;
                const float v = acc[mb][nb][r];
                if (OUT_BF16) {
                    u16* C = (u16*)C0 + (size_t)blockIdx.z * NROWS * DMODEL;
                    C[(size_t)row * DMODEL + col] = f2bf(v);
                } else {
                    float* C = (float*)C0;
                    C[(size_t)row * DMODEL + col] = v;
                }
            }
}

// ---------- RoPE in place on bf16 q or k ----------
__global__ __launch_bounds__(256) void rope_kernel(u16* __restrict__ qw, u16* __restrict__ kw) {
    const int row = blockIdx.x;
    const int spos = row & (SQ - 1);
    u16* buf = blockIdx.y ? kw : qw;
    for (int idx = threadIdx.x; idx < 1024; idx += 256) {
        const int h2 = idx >> 5, i = idx & 31;
        const size_t base = (size_t)row * DMODEL + h2 * 64 + 2 * i;
        const float x1 = bf2f(buf[base]), x2 = bf2f(buf[base + 1]);
        const float f = (float)spos * exp2f(-0.41524101186092034f * (float)i);
        const float c = cosf(f), sn = sinf(f);
        buf[base]     = f2bf(x1 * c - x2 * sn);
        buf[base + 1] = f2bf(x2 * c + x1 * sn);
    }
}

// ---------- lambda scalar ----------
__global__ void lam_kernel(const float* __restrict__ lq1, const float* __restrict__ lk1,
                           const float* __restrict__ lq2, const float* __restrict__ lk2,
                           float* __restrict__ out) {
    const int l = threadIdx.x;  // 64
    float v1 = lq1[l] * lk1[l];
    float v2 = lq2[l] * lk2[l];
#pragma unroll
    for (int off = 32; off; off >>= 1) {
        v1 += __shfl_xor(v1, off);
        v2 += __shfl_xor(v2, off);
    }
    if (l == 0) out[0] = __expf(v1) - __expf(v2) + LAMBDA_INIT;
}

// ---------- V transpose: vtg[bh][128 dims][2048 keys] ----------
__global__ __launch_bounds__(256) void vtrans(const u16* __restrict__ vb, u16* __restrict__ vtg) {
    __shared__ u16 tile[64][72];
    const int bh = blockIdx.z;
    const int b = bh >> 4, h = bh & 15;
    const int s0 = blockIdx.x * 64, d0 = blockIdx.y * 64;
    const size_t rowbase = (size_t)b * SQ;
    const int tid = threadIdx.x;
#pragma unroll
    for (int it = 0; it < 2; ++it) {
        const int slot = it * 256 + tid;
        const int key = slot >> 3, dg = slot & 7;
        *(uint4*)&tile[key][dg * 8] =
            *(const uint4*)(vb + (rowbase + s0 + key) * DMODEL + h * 128 + d0 + dg * 8);
    }
    __syncthreads();
#pragma unroll
    for (int it = 0; it < 2; ++it) {
        const int slot = it * 256 + tid;
        const int d = slot >> 3, kg = slot & 7;
        u16 e[8];
#pragma unroll
        for (int j = 0; j < 8; ++j) e[j] = tile[kg * 8 + j][d];
        uint4 o;
        o.x = (u32)e[0] | ((u32)e[1] << 16);
        o.y = (u32)e[2] | ((u32)e[3] << 16);
        o.z = (u32)e[4] | ((u32)e[5] << 16);
        o.w = (u32)e[6] | ((u32)e[7] << 16);
        *(uint4*)(vtg + ((size_t)bh * 128 + d0 + d) * SQ + s0 + kg * 8) = o;
    }
}

// ---------- MFMA flash attention (dual softmax) + fused combine/RMSNorm ----------
// grid (32 bh, 16 pairs): bh fastest -> XCD r sees only bh%8==r (4 bh, 4 MB K+V = L2).
// Balanced pairing: block does strips {pair, 31-pair} = 33 tiles total.
// SINGLE-buffer async staging (global_load_lds): stage -> barrier (vmcnt drain)
// -> compute -> barrier. 41 KB LDS -> 3 blocks/CU; cross-block overlap hides
// the stage drain (m114). Dbuf was tried (R3): compiler's conservative
// vmcnt(0)-before-ds_read voids the overlap while halving occupancy.
__global__ __launch_bounds__(256) void attn_kernel(const u16* __restrict__ qw,
                                                   const u16* __restrict__ kw,
                                                   const u16* __restrict__ vtg,
                                                   const float* __restrict__ lamp,
                                                   const float* __restrict__ lnw,
                                                   const float* __restrict__ lnb,
                                                   u16* __restrict__ yb) {
    __shared__ u16 Ks[64 * 128];    // [key][16 swizzled col-groups of 8]
    __shared__ u16 Vts[128 * 64];   // [dim][8 swizzled key-groups of 8]
    __shared__ u16 Pls[4][16 * 72]; // per-wave [q16][64 keys + 8 pad]

    const int tid = threadIdx.x, lane = tid & 63, wave = tid >> 6;
    const int l15 = lane & 15, quad = lane >> 4;
    const int bh = blockIdx.x, b = bh >> 4, h = bh & 15;
    const int pair = blockIdx.y;
    const size_t rowbase = (size_t)b * SQ;
    const int coff = h * 128;
    const float lam = lamp[0];

    // per-lane staging source offsets (swizzle applied on the SOURCE side so the
    // lane-contiguous LDS scatter lands data at the swizzled slot)
    int kOff[4], vOff[4];
#pragma unroll
    for (int i = 0; i < 4; ++i) {
        const int cK  = wave * 4 + i;
        const int key = cK * 4 + (lane >> 4);          // 4 key-rows per chunk
        const int cg  = (lane & 15) ^ (key & 7);       // logical col-group for phys slot lane&15
        kOff[i] = key * DMODEL + coff + cg * 8;
        const int dd  = cK * 8 + (lane >> 3);          // 8 dim-rows per chunk
        const int kg  = (lane & 7) ^ (lane >> 3);      // dd&7 == lane>>3
        vOff[i] = dd * SQ + kg * 8;
    }
    const size_t kBase = rowbase * DMODEL;
    const size_t vBase = (size_t)bh * 128 * SQ;

    auto stageKV = [&](int t0) {
#pragma unroll
        for (int i = 0; i < 4; ++i) {
            gload_lds16(kw + kBase + (size_t)t0 * DMODEL + kOff[i], &Ks[(wave * 4 + i) * 512]);
            gload_lds16(vtg + vBase + t0 + vOff[i], &Vts[(wave * 4 + i) * 512]);
        }
    };

#pragma unroll 1
    for (int s = 0; s < 2; ++s) {
        const int strip = s ? (31 - pair) : pair;
        const int q0 = strip * 64;
        const int nt = strip + 1;

        // Q fragments (A layout: m=lane&15, k=quad*8+j), persistent per strip
        bf16x8 qf[2][2];
        {
            const size_t qbase = (rowbase + q0 + wave * 16 + l15) * DMODEL + coff + quad * 8;
#pragma unroll
            for (int hf = 0; hf < 2; ++hf)
#pragma unroll
                for (int ks = 0; ks < 2; ++ks)
                    qf[hf][ks] = *(const bf16x8*)(qw + qbase + hf * 64 + ks * 32);
        }

        f32x4 O[2][8] = {};
        float mm[2][4], ll[2][4];
#pragma unroll
        for (int hf = 0; hf < 2; ++hf)
#pragma unroll
            for (int r = 0; r < 4; ++r) { mm[hf][r] = -1e30f; ll[hf][r] = 0.f; }

        for (int t = 0; t < nt; ++t) {
            const int t0 = t * 64;
            stageKV(t0);
            __syncthreads();            // drains the LDS-DMA (vmcnt) + syncs
            const bool maskt = (t == nt - 1);   // only diagonal tile needs masking

#pragma unroll
            for (int hf = 0; hf < 2; ++hf) {
                // ---- S = Q_hf K_hf^T (16 q x 64 keys per wave), log2-domain scale ----
                f32x4 S[4] = {};
#pragma unroll
                for (int nb = 0; nb < 4; ++nb)
#pragma unroll
                    for (int ks = 0; ks < 2; ++ks) {
                        const int cgp = (hf * 8 + ks * 4 + quad) ^ (l15 & 7);
                        bf16x8 kf = *(const bf16x8*)&Ks[(nb * 16 + l15) * 128 + cgp * 8];
                        S[nb] = __builtin_amdgcn_mfma_f32_16x16x32_bf16(qf[hf][ks], kf, S[nb], 0, 0, 0);
                    }
                // ---- scale (log2 domain) + causal mask + row max ----
                float mt[4];
#pragma unroll
                for (int r = 0; r < 4; ++r) mt[r] = -1e30f;
#pragma unroll
                for (int nb = 0; nb < 4; ++nb)
#pragma unroll
                    for (int r = 0; r < 4; ++r) {
                        float sv = S[nb][r] * CSC;
                        if (maskt && (nb * 16 + l15 > wave * 16 + quad * 4 + r)) sv = -1e30f;
                        S[nb][r] = sv;
                        mt[r] = fmaxf(mt[r], sv);
                    }
#pragma unroll
                for (int r = 0; r < 4; ++r)
#pragma unroll
                    for (int off = 1; off < 16; off <<= 1)
                        mt[r] = fmaxf(mt[r], __shfl_xor(mt[r], off));
                // ---- online softmax update (exp2; truncation-quantized bf16 P) ----
                float alpha[4], ps[4];
#pragma unroll
                for (int r = 0; r < 4; ++r) {
                    const float mn = fmaxf(mm[hf][r], mt[r]);
                    alpha[r] = exp2f(mm[hf][r] - mn);
                    mm[hf][r] = mn;
                    ps[r] = 0.f;
                }
#pragma unroll
                for (int nb = 0; nb < 4; ++nb)
#pragma unroll
                    for (int r = 0; r < 4; ++r) {
                        const float p = exp2f(S[nb][r] - mm[hf][r]);
                        const u32 pu = __builtin_bit_cast(u32, p);
                        ps[r] += __builtin_bit_cast(float, pu & 0xffff0000u); // quantized sum
                        Pls[wave][(quad * 4 + r) * 72 + nb * 16 + l15] = (u16)(pu >> 16);
                    }
#pragma unroll
                for (int r = 0; r < 4; ++r) {
#pragma unroll
                    for (int off = 1; off < 16; off <<= 1) ps[r] += __shfl_xor(ps[r], off);
                    ll[hf][r] = ll[hf][r] * alpha[r] + ps[r];
                }
                // ---- rescale O, then O += P V ----
#pragma unroll
                for (int nb = 0; nb < 8; ++nb)
#pragma unroll
                    for (int r = 0; r < 4; ++r) O[hf][nb][r] *= alpha[r];
                bf16x8 pf[2];
#pragma unroll
                for (int ks = 0; ks < 2; ++ks)
                    pf[ks] = *(const bf16x8*)&Pls[wave][l15 * 72 + ks * 32 + quad * 8];
#pragma unroll
                for (int nb = 0; nb < 8; ++nb)
#pragma unroll
                    for (int ks = 0; ks < 2; ++ks) {
                        const int kgp = (ks * 4 + quad) ^ (l15 & 7);
                        bf16x8 vf = *(const bf16x8*)&Vts[(nb * 16 + l15) * 64 + kgp * 8];
                        O[hf][nb] = __builtin_amdgcn_mfma_f32_16x16x32_bf16(pf[ks], vf, O[hf][nb], 0, 0, 0);
                    }
            }
            __syncthreads();            // protect Ks/Vts before next stage
        }

        // ---- epilogue: y = rmsnorm(O1/l1 - lam*O2/l2) * w + b, * OUT_SCALE ----
        float inl1[4], inl2[4];
#pragma unroll
        for (int r = 0; r < 4; ++r) { inl1[r] = 1.f / ll[0][r]; inl2[r] = 1.f / ll[1][r]; }
        float vv[8][4], ss[4] = {0.f, 0.f, 0.f, 0.f};
#pragma unroll
        for (int nb = 0; nb < 8; ++nb)
#pragma unroll
            for (int r = 0; r < 4; ++r) {
                const float v = O[0][nb][r] * inl1[r] - lam * O[1][nb][r] * inl2[r];
                vv[nb][r] = v;
                ss[r] += v * v;
            }
#pragma unroll
        for (int r = 0; r < 4; ++r) {
#pragma unroll
            for (int off = 1; off < 16; off <<= 1) ss[r] += __shfl_xor(ss[r], off);
            ss[r] = rsqrtf(ss[r] * (1.f / 128.f) + 1e-8f) * OUT_SCALE;
        }
#pragma unroll
        for (int nb = 0; nb < 8; ++nb) {
            const int d = nb * 16 + l15;
            const float w = lnw[d], bb = lnb[d] * OUT_SCALE;
#pragma unroll
            for (int r = 0; r < 4; ++r) {
                const size_t row = rowbase + q0 + wave * 16 + quad * 4 + r;
                yb[row * DMODEL + coff + d] = f2bf(vv[nb][r] * ss[r] * w + bb);
            }
        }
    }
}

// ---------- workspace layout (bytes) ----------
#define WT_OFF   0ull                 // 4 x 2048x2048 bf16 = 32 MB
#define XB_OFF   33554432ull          // 4096x2048 bf16 (xb, reused as yb)
#define Q_OFF    50331648ull          // 4096x2048 bf16
#define K_OFF    67108864ull
#define V_OFF    83886080ull
#define VT_OFF   100663296ull         // 32 bh x 128 x 2048 bf16 = 16 MB
#define LAM_OFF  117440512ull
#define WS_NEED  117440768ull

extern "C" void kernel_launch(void* const* d_in, const int* in_sizes, int n_in,
                              void* d_out, int out_size, void* d_ws, size_t ws_size,
                              hipStream_t stream) {
    if (ws_size < WS_NEED) return;
    const float* x   = (const float*)d_in[0];
    const float* Wq  = (const float*)d_in[1];
    const float* Wk  = (const float*)d_in[2];
    const float* Wv  = (const float*)d_in[3];
    const float* Wo  = (const float*)d_in[4];
    const float* lq1 = (const float*)d_in[5];
    const float* lk1 = (const float*)d_in[6];
    const float* lq2 = (const float*)d_in[7];
    const float* lk2 = (const float*)d_in[8];
    const float* lnw = (const float*)d_in[9];
    const float* lnb = (const float*)d_in[10];

    char* ws = (char*)d_ws;
    u16* wt  = (u16*)(ws + WT_OFF);
    u16* xb  = (u16*)(ws + XB_OFF);   // also yb after attention
    u16* qb  = (u16*)(ws + Q_OFF);
    u16* kb  = (u16*)(ws + K_OFF);
    u16* vb  = (u16*)(ws + V_OFF);
    u16* vtg = (u16*)(ws + VT_OFF);
    float* lam = (float*)(ws + LAM_OFF);
    float* out = (float*)d_out;

    // 1. transpose + convert weights
    transpose_w<<<dim3(64, 64, 4), dim3(32, 8, 1), 0, stream>>>(Wq, Wk, Wv, Wo, wt);
    // 2. x -> bf16
    cvt_x<<<dim3(4096), dim3(256), 0, stream>>>(x, xb);
    // 3. q,k,v GEMMs (bf16 out)
    gemm_bt<true><<<dim3(16, 32, 3), dim3(256), 0, stream>>>(xb, wt, qb);
    // 4. RoPE in place on q and k
    rope_kernel<<<dim3(4096, 2), dim3(256), 0, stream>>>(qb, kb);
    // 5. lambda
    lam_kernel<<<dim3(1), dim3(64), 0, stream>>>(lq1, lk1, lq2, lk2, lam);
    // 6. V transpose for PV MFMA B-operand
    vtrans<<<dim3(32, 2, 32), dim3(256), 0, stream>>>(vb, vtg);
    // 7. MFMA flash attention (single-buffer async staging, XCD-local grid) -> yb
    attn_kernel<<<dim3(32, 16), dim3(256), 0, stream>>>(qb, kb, vtg, lam, lnw, lnb, xb);
    // 8. out = y @ Wo  (f32 out)
    gemm_bt<false><<<dim3(16, 32, 1), dim3(256), 0, stream>>>(xb, wt + 3ull * DMODEL * DMODEL, out);
}